// Round 1
// baseline (367.801 us; speedup 1.0000x reference)
//
#include <hip/hip_runtime.h>

// LengthRegulator (FastSpeech): expanded gather + mel_len + mel_mask.
// Outputs concatenated flat in d_out as float32:
//   [0, B*max_len*D)                      expanded
//   [B*max_len*D, +B)                     mel_len (as float)
//   [B*max_len*D + B, +B*max_len)         mel_mask (0.0 / 1.0)
//
// R4 -> R5: replace token-driven scatter (+ separate tail-zero pass) with an
// output-driven GATHER: one block per TILE=64 consecutive output frames,
// csum row staged in LDS, per-frame binary search (== jnp.searchsorted
// side='right'), then perfectly-sequential nontemporal float4 stores.
// Zero-pad frames and mask are produced by the same uniform loop — no tail
// blocks, no scattered mask writes, balanced blocks.

#define S_TOK 1024  // tokens per sequence
#define B_SZ  32    // batch
#define TILE  64    // output frames per block
#define BLK   256   // threads per block

typedef float vfloat4 __attribute__((ext_vector_type(4)));
typedef int   vint4   __attribute__((ext_vector_type(4)));

// One wave per batch: 16 durations/lane serial prefix + wave shuffle scan.
__global__ __launch_bounds__(64)
void lr_scan_kernel(const int* __restrict__ dur,
                    int* __restrict__ csum,
                    float* __restrict__ mel_len_out) {
    const int b = blockIdx.x;
    const int lane = threadIdx.x;
    const int* __restrict__ d = dur + b * S_TOK;

    int v[16];
    int sum = 0;
#pragma unroll
    for (int k = 0; k < 16; ++k) {
        v[k] = d[lane * 16 + k];
        sum += v[k];
    }
    // inclusive within-lane prefix
    int run = 0;
#pragma unroll
    for (int k = 0; k < 16; ++k) { run += v[k]; v[k] = run; }

    // wave inclusive scan of per-lane sums
    int tot = sum;
#pragma unroll
    for (int off = 1; off < 64; off <<= 1) {
        int n = __shfl_up(tot, off, 64);
        if (lane >= off) tot += n;
    }
    const int excl = tot - sum;

#pragma unroll
    for (int k = 0; k < 16; ++k)
        csum[b * S_TOK + lane * 16 + k] = v[k] + excl;
    if (lane == 63) mel_len_out[b] = (float)tot;
}

// Output-driven gather: blockIdx.x = frame tile, blockIdx.y = batch.
// Frame t takes row idx = first i with csum[i] > t (searchsorted right),
// or zeros when t >= mel. Mask written coalesced by threads [0,TILE).
__global__ __launch_bounds__(BLK)
void lr_gather_kernel(const float* __restrict__ x,
                      const int* __restrict__ csum,
                      float* __restrict__ out,
                      float* __restrict__ mask,
                      int D, int max_len) {
    __shared__ int c_lds[S_TOK];
    __shared__ int src_lds[TILE];

    const int b   = blockIdx.y;
    const int tid = threadIdx.x;
    const int t0  = blockIdx.x * TILE;

    // stage csum row: 256 threads x int4 = 4 KB
    ((vint4*)c_lds)[tid] = ((const vint4*)(csum + b * S_TOK))[tid];
    __syncthreads();
    const int mel = c_lds[S_TOK - 1];

    if (tid < TILE) {
        const int t = t0 + tid;
        int src = -1;
        if (t < mel) {
            int lo = 0, hi = S_TOK;  // first i with c[i] > t
            while (lo < hi) {
                const int mid = (lo + hi) >> 1;
                if (c_lds[mid] <= t) lo = mid + 1; else hi = mid;
            }
            src = lo;                 // t < mel => lo <= S_TOK-1
        }
        src_lds[tid] = src;
        if (t < max_len)
            mask[(size_t)b * max_len + t] = (t >= mel) ? 1.0f : 0.0f;
    }
    __syncthreads();

    const int half = tid >> 7;     // which of the 2 frames this pass
    const int l    = tid & 127;    // float4 slot within frame
    const int d4   = D >> 2;       // 128 for D=512
    const float* __restrict__ xb = x + (size_t)b * S_TOK * D;
    float* __restrict__ ob       = out + (size_t)b * max_len * D;

#pragma unroll 4
    for (int i = 0; i < TILE / 2; ++i) {
        const int f = 2 * i + half;
        const int t = t0 + f;
        if (t < max_len) {
            const int src = src_lds[f];
            for (int j = l; j < d4; j += BLK / 2) {
                vfloat4 v = (vfloat4)(0.f);
                if (src >= 0)
                    v = ((const vfloat4*)(xb + (size_t)src * D))[j];
                __builtin_nontemporal_store(
                    v, (vfloat4*)(ob + (size_t)t * D) + j);
            }
        }
    }
}

extern "C" void kernel_launch(void* const* d_in, const int* in_sizes, int n_in,
                              void* d_out, int out_size, void* d_ws, size_t ws_size,
                              hipStream_t stream) {
    const float* x = (const float*)d_in[0];
    const int* dur = (const int*)d_in[1];
    float* out = (float*)d_out;

    const int D = in_sizes[0] / in_sizes[1];                 // 512
    const int max_len = (out_size / B_SZ - 1) / (D + 1);     // data-dependent, from out_size

    int* csum = (int*)d_ws;                                  // B*S ints = 128 KB
    float* mel_len = out + (size_t)B_SZ * max_len * D;
    float* mask = mel_len + B_SZ;

    lr_scan_kernel<<<B_SZ, 64, 0, stream>>>(dur, csum, mel_len);

    dim3 ggrid((unsigned)((max_len + TILE - 1) / TILE), (unsigned)B_SZ);
    lr_gather_kernel<<<ggrid, BLK, 0, stream>>>(x, csum, out, mask, D, max_len);
}

// Round 2
// 362.898 us; speedup vs baseline: 1.0135x; 1.0135x over previous
//
#include <hip/hip_runtime.h>

// LengthRegulator (FastSpeech): expanded gather + mel_len + mel_mask.
// Outputs concatenated flat in d_out as float32:
//   [0, B*max_len*D)                      expanded
//   [B*max_len*D, +B)                     mel_len (as float)
//   [B*max_len*D + B, +B*max_len)         mel_mask (0.0 / 1.0)
//
// R5 -> R6: revert to the (faster) token-scatter core, but make it a
// PERSISTENT grid-stride kernel: 2048 blocks set up base pointers once and
// loop over ~8 token jobs each (33K short blocks -> 2048 long blocks, deep
// memory-level parallelism). Mask is now one fully-coalesced frame-driven
// sweep (replaces the per-token 4B scatter + tail mask), and pad-row
// zeroing is folded into the same half-block job counter.

#define S_TOK 1024  // tokens per sequence
#define B_SZ  32    // batch
#define BLK   256   // threads per block (phase-2 kernel)
#define GRID2 2048  // persistent blocks (8 per CU)

typedef float vfloat4 __attribute__((ext_vector_type(4)));

// One wave per batch: 16 durations/lane serial prefix + wave shuffle scan.
__global__ __launch_bounds__(64)
void lr_scan_kernel(const int* __restrict__ dur,
                    int* __restrict__ csum,
                    float* __restrict__ mel_len_out) {
    const int b = blockIdx.x;
    const int lane = threadIdx.x;
    const int* __restrict__ d = dur + b * S_TOK;

    int v[16];
    int sum = 0;
#pragma unroll
    for (int k = 0; k < 16; ++k) {
        v[k] = d[lane * 16 + k];
        sum += v[k];
    }
    // inclusive within-lane prefix
    int run = 0;
#pragma unroll
    for (int k = 0; k < 16; ++k) { run += v[k]; v[k] = run; }

    // wave inclusive scan of per-lane sums
    int tot = sum;
#pragma unroll
    for (int off = 1; off < 64; off <<= 1) {
        int n = __shfl_up(tot, off, 64);
        if (lane >= off) tot += n;
    }
    const int excl = tot - sum;

#pragma unroll
    for (int k = 0; k < 16; ++k)
        csum[b * S_TOK + lane * 16 + k] = v[k] + excl;
    if (lane == 63) mel_len_out[b] = (float)tot;
}

// Persistent fused kernel: coalesced mask sweep, then grid-stride token
// scatter (one token per 128-thread half-block per iteration), then
// pad-row zero jobs on the same counter.
__global__ __launch_bounds__(BLK)
void lr_persist_kernel(const float* __restrict__ x,
                       const int* __restrict__ csum,
                       float* __restrict__ out,
                       float* __restrict__ mask,
                       int D, int max_len, int pad_rows) {
    const int tid = threadIdx.x;
    const int d4 = D >> 2;  // 128 for D=512

    // ---- 1) mel_mask: fully coalesced 4B stores --------------------------
    const int total_mask = B_SZ * max_len;
    for (int idx = blockIdx.x * BLK + tid; idx < total_mask;
         idx += gridDim.x * BLK) {
        const int b = idx / max_len;
        const int t = idx - b * max_len;
        const int mel = csum[b * S_TOK + S_TOK - 1];
        mask[idx] = (t >= mel) ? 1.0f : 0.0f;
    }

    // ---- 2) token scatter: half-block (128 threads) per token job --------
    const int half = tid >> 7;   // 0 / 1
    const int l    = tid & 127;  // float4 slot within a frame row
    const int stride = gridDim.x * 2;
    const int total_tok = B_SZ * S_TOK;

    int job = blockIdx.x * 2 + half;
    for (; job < total_tok; job += stride) {
        const int b = job >> 10;           // job / S_TOK
        const int s = job & (S_TOK - 1);
        const int* __restrict__ c = csum + b * S_TOK;
        const int base = (s == 0) ? 0 : c[s - 1];
        const int dur  = c[s] - base;

        const vfloat4 v =
            ((const vfloat4*)(x + ((size_t)b * S_TOK + s) * (size_t)D))[l];
        vfloat4* __restrict__ o =
            (vfloat4*)(out + ((size_t)b * max_len + base) * (size_t)D) + l;
        for (int r = 0; r < dur; ++r)
            __builtin_nontemporal_store(v, o + (size_t)r * d4);
    }

    // ---- 3) pad-row zeroing: same job counter, rows t = mel_b + k --------
    const int total_pad = B_SZ * pad_rows;
    for (int pj = job - total_tok; pj < total_pad; pj += stride) {
        const int b = pj / pad_rows;
        const int k = pj - b * pad_rows;
        const int t = csum[b * S_TOK + S_TOK - 1] + k;
        if (t < max_len) {
            vfloat4* __restrict__ o =
                (vfloat4*)(out + ((size_t)b * max_len + t) * (size_t)D) + l;
            __builtin_nontemporal_store((vfloat4)(0.f), o);
        }
    }
}

extern "C" void kernel_launch(void* const* d_in, const int* in_sizes, int n_in,
                              void* d_out, int out_size, void* d_ws, size_t ws_size,
                              hipStream_t stream) {
    const float* x = (const float*)d_in[0];
    const int* dur = (const int*)d_in[1];
    float* out = (float*)d_out;

    const int D = in_sizes[0] / in_sizes[1];                 // 512
    const int max_len = (out_size / B_SZ - 1) / (D + 1);     // data-dependent, from out_size

    int* csum = (int*)d_ws;                                  // B*S ints = 128 KB
    float* mel_len = out + (size_t)B_SZ * max_len * D;
    float* mask = mel_len + B_SZ;

    lr_scan_kernel<<<B_SZ, 64, 0, stream>>>(dur, csum, mel_len);

    // mel_b >= S_TOK (dur >= 1), so per-batch pad rows <= max_len - S_TOK.
    const int pad_rows = (max_len > S_TOK) ? (max_len - S_TOK + 1) : 1;
    lr_persist_kernel<<<GRID2, BLK, 0, stream>>>(x, csum, out, mask,
                                                 D, max_len, pad_rows);
}

// Round 3
// 357.314 us; speedup vs baseline: 1.0293x; 1.0156x over previous
//
#include <hip/hip_runtime.h>

// LengthRegulator (FastSpeech): expanded gather + mel_len + mel_mask.
// Outputs concatenated flat in d_out as float32:
//   [0, B*max_len*D)                      expanded
//   [B*max_len*D, +B)                     mel_len (as float)
//   [B*max_len*D + B, +B*max_len)         mel_mask (0.0 / 1.0)
//
// R6 -> R7: back to the fastest (R4) fresh-block scatter structure, with two
// changes: (1) PLAIN stores instead of __builtin_nontemporal_store — the
// discriminating experiment for whether the `nt` path was throttling all
// three previous designs; (2) mel_mask is now written by the tail blocks as
// a fully-coalesced sweep (replaces the <=8-float scatter per token block).

#define S_TOK 1024  // tokens per sequence
#define B_SZ  32    // batch
#define BLK   128   // threads per block (fused kernel): one float4 lane per D/4

typedef float vfloat4 __attribute__((ext_vector_type(4)));

// One wave per batch: 16 durations/lane serial prefix + wave shuffle scan.
__global__ __launch_bounds__(64)
void lr_scan_kernel(const int* __restrict__ dur,
                    int* __restrict__ csum,
                    float* __restrict__ mel_len_out) {
    const int b = blockIdx.x;
    const int lane = threadIdx.x;
    const int* __restrict__ d = dur + b * S_TOK;

    int v[16];
    int sum = 0;
#pragma unroll
    for (int k = 0; k < 16; ++k) {
        v[k] = d[lane * 16 + k];
        sum += v[k];
    }
    // inclusive within-lane prefix
    int run = 0;
#pragma unroll
    for (int k = 0; k < 16; ++k) { run += v[k]; v[k] = run; }

    // wave inclusive scan of per-lane sums
    int tot = sum;
#pragma unroll
    for (int off = 1; off < 64; off <<= 1) {
        int n = __shfl_up(tot, off, 64);
        if (lane >= off) tot += n;
    }
    const int excl = tot - sum;

#pragma unroll
    for (int k = 0; k < 16; ++k)
        csum[b * S_TOK + lane * 16 + k] = v[k] + excl;
    if (lane == 63) mel_len_out[b] = (float)tot;
}

// Fused scatter + tail-zero + coalesced mask.
// blockIdx.x in [0, S_TOK): token s scatter — copy x[b,s,:] to frames
//   [c[s-1], c[s]).
// blockIdx.x in [S_TOK, S_TOK+tail): job j = blockIdx.x - S_TOK:
//   - zero-fill 4 pad frames starting at mel + 4*j
//   - cooperative coalesced mask sweep over frames [0, max_len)
__global__ __launch_bounds__(BLK)
void lr_fused_kernel(const float* __restrict__ x,
                     const int* __restrict__ csum,
                     float* __restrict__ out,
                     float* __restrict__ mask,
                     int D, int max_len, int tail_blocks) {
    const int b = blockIdx.y;
    const int tid = threadIdx.x;
    const int* __restrict__ c = csum + b * S_TOK;
    const int d4 = D >> 2;

    if (blockIdx.x < S_TOK) {
        const int s = blockIdx.x;
        const int base = (s == 0) ? 0 : c[s - 1];
        const int dur = c[s] - base;

        const vfloat4 v =
            ((const vfloat4*)(x + ((size_t)b * S_TOK + s) * (size_t)D))[tid];
        vfloat4* __restrict__ o =
            (vfloat4*)(out + ((size_t)b * max_len + base) * (size_t)D) + tid;
        for (int r = 0; r < dur; ++r)
            o[(size_t)r * d4] = v;
    } else {
        const int j = blockIdx.x - S_TOK;
        const int mel = c[S_TOK - 1];

        // pad-frame zeroing: 4 rows per tail job
        const int t0 = mel + j * 4;
        const vfloat4 z = (vfloat4)(0.f);
#pragma unroll
        for (int k = 0; k < 4; ++k) {
            const int t = t0 + k;
            if (t < max_len)
                ((vfloat4*)(out + ((size_t)b * max_len + t) * (size_t)D))[tid] = z;
        }

        // coalesced mask sweep across the tail-block group
        for (int idx = j * BLK + tid; idx < max_len; idx += tail_blocks * BLK)
            mask[(size_t)b * max_len + idx] = (idx >= mel) ? 1.0f : 0.0f;
    }
}

extern "C" void kernel_launch(void* const* d_in, const int* in_sizes, int n_in,
                              void* d_out, int out_size, void* d_ws, size_t ws_size,
                              hipStream_t stream) {
    const float* x = (const float*)d_in[0];
    const int* dur = (const int*)d_in[1];
    float* out = (float*)d_out;

    const int D = in_sizes[0] / in_sizes[1];                 // 512
    const int max_len = (out_size / B_SZ - 1) / (D + 1);     // data-dependent, from out_size

    int* csum = (int*)d_ws;                                  // B*S ints = 128 KB
    float* mel_len = out + (size_t)B_SZ * max_len * D;
    float* mask = mel_len + B_SZ;

    lr_scan_kernel<<<B_SZ, 64, 0, stream>>>(dur, csum, mel_len);

    // tail worst case: mel >= S_TOK (dur >= 1), so at most
    // ceil((max_len - S_TOK)/4) tail blocks are ever needed; +1 slack.
    const int tail_blocks = (max_len > S_TOK) ? ((max_len - S_TOK + 3) / 4 + 1) : 1;
    dim3 fgrid((unsigned)(S_TOK + tail_blocks), (unsigned)B_SZ);
    lr_fused_kernel<<<fgrid, BLK, 0, stream>>>(x, csum, out, mask,
                                               D, max_len, tail_blocks);
}